// Round 1
// baseline (746.461 us; speedup 1.0000x reference)
//
#include <hip/hip_runtime.h>
#include <math.h>

#define T_LEN 256
#define BATCH 32
#define HID   768
#define GH    384   // 3*LSTM_H
#define LH    128   // LSTM_H
#define NLAB  9
#define M_TOT (T_LEN*BATCH)  // 8192

// ---------------- K1: xp[t][b][0:768] = emb[ids] @ [Wih_f;Wih_b]^T + bias ----
// 128x128 tile, BK=8, 256 threads, 8x8 per thread. m = t*32+b.
__global__ __launch_bounds__(256) void k_gemm_xp(
    const int* __restrict__ ids, const float* __restrict__ emb,
    const float* __restrict__ Wf, const float* __restrict__ Wb,
    const float* __restrict__ bihf, const float* __restrict__ bihb,
    float* __restrict__ xp)
{
  __shared__ __align__(16) float As[8*128];
  __shared__ __align__(16) float Bs[8*128];
  const int tid = threadIdx.x;
  const int m0 = blockIdx.y * 128, n0 = blockIdx.x * 128;
  const int lrow = tid >> 1, c4 = (tid & 1) * 4;

  const int gm = m0 + lrow;
  const int tt = gm >> 5, bb = gm & 31;
  const int tok = ids[bb * T_LEN + tt];
  const float* aptr = emb + (size_t)tok * HID + c4;
  const int gn = n0 + lrow;
  const float* bptr = (gn < GH ? Wf + (size_t)gn * HID
                               : Wb + (size_t)(gn - GH) * HID) + c4;

  const int tx = tid & 15, ty = tid >> 4;
  float acc[8][8];
#pragma unroll
  for (int u = 0; u < 8; ++u)
#pragma unroll
    for (int v = 0; v < 8; ++v) acc[u][v] = 0.f;

  for (int k0 = 0; k0 < HID; k0 += 8) {
    float4 av = *reinterpret_cast<const float4*>(aptr + k0);
    float4 bv = *reinterpret_cast<const float4*>(bptr + k0);
    __syncthreads();
    As[(c4+0)*128 + lrow] = av.x;  As[(c4+1)*128 + lrow] = av.y;
    As[(c4+2)*128 + lrow] = av.z;  As[(c4+3)*128 + lrow] = av.w;
    Bs[(c4+0)*128 + lrow] = bv.x;  Bs[(c4+1)*128 + lrow] = bv.y;
    Bs[(c4+2)*128 + lrow] = bv.z;  Bs[(c4+3)*128 + lrow] = bv.w;
    __syncthreads();
#pragma unroll
    for (int kk = 0; kk < 8; ++kk) {
      float4 a0 = *reinterpret_cast<const float4*>(&As[kk*128 + ty*4]);
      float4 a1 = *reinterpret_cast<const float4*>(&As[kk*128 + 64 + ty*4]);
      float4 b0 = *reinterpret_cast<const float4*>(&Bs[kk*128 + tx*4]);
      float4 b1 = *reinterpret_cast<const float4*>(&Bs[kk*128 + 64 + tx*4]);
      float a[8] = {a0.x,a0.y,a0.z,a0.w,a1.x,a1.y,a1.z,a1.w};
      float b[8] = {b0.x,b0.y,b0.z,b0.w,b1.x,b1.y,b1.z,b1.w};
#pragma unroll
      for (int u = 0; u < 8; ++u)
#pragma unroll
        for (int v = 0; v < 8; ++v)
          acc[u][v] = fmaf(a[u], b[v], acc[u][v]);
    }
  }

  float bb8[8];
#pragma unroll
  for (int v = 0; v < 8; ++v) {
    int gc = n0 + tx*4 + (v & 3) + ((v >> 2) << 6);
    bb8[v] = (gc < GH) ? bihf[gc] : bihb[gc - GH];
  }
#pragma unroll
  for (int u = 0; u < 8; ++u) {
    int row = m0 + ty*4 + (u & 3) + ((u >> 2) << 6);
    float* orow = xp + (size_t)row * HID + n0;
    float4 o0, o1;
    o0.x = acc[u][0] + bb8[0]; o0.y = acc[u][1] + bb8[1];
    o0.z = acc[u][2] + bb8[2]; o0.w = acc[u][3] + bb8[3];
    o1.x = acc[u][4] + bb8[4]; o1.y = acc[u][5] + bb8[5];
    o1.z = acc[u][6] + bb8[6]; o1.w = acc[u][7] + bb8[7];
    *reinterpret_cast<float4*>(orow + tx*4)      = o0;
    *reinterpret_cast<float4*>(orow + 64 + tx*4) = o1;
  }
}

// ---------------- K2: bidirectional GRU recurrence -------------------------
// 64 blocks = (dir, batch); 384 threads; Whh row register-resident.
__global__ __launch_bounds__(384, 2) void k_gru(
    const float* __restrict__ xp,
    const float* __restrict__ Whhf, const float* __restrict__ Whhb,
    const float* __restrict__ bhhf, const float* __restrict__ bhhb,
    float* __restrict__ hbuf)
{
  __shared__ __align__(16) float hs[LH];
  __shared__ float sA[GH];
  __shared__ float sX[GH];
  const int g   = threadIdx.x;
  const int bd  = blockIdx.x;
  const int dir = bd >> 5, b = bd & 31;
  const float* Whh = dir ? Whhb : Whhf;
  const float* bhh = dir ? bhhb : bhhf;

  float wr[LH];
#pragma unroll
  for (int k = 0; k < LH; k += 4) {
    float4 w4 = *reinterpret_cast<const float4*>(Whh + (size_t)g * LH + k);
    wr[k] = w4.x; wr[k+1] = w4.y; wr[k+2] = w4.z; wr[k+3] = w4.w;
  }
  const float bg = bhh[g];
  if (g < LH) hs[g] = 0.f;

  const int t0 = dir ? (T_LEN - 1) : 0;
  const int dt = dir ? -1 : 1;
  const int xoff = dir * GH;
  float xv = xp[((size_t)t0 * BATCH + b) * HID + xoff + g];
  __syncthreads();

  int t = t0;
  for (int step = 0; step < T_LEN; ++step) {
    sX[g] = xv;
    const int tn = t + dt;
    if (step < T_LEN - 1)
      xv = xp[((size_t)tn * BATCH + b) * HID + xoff + g];  // prefetch next

    float a0 = 0.f, a1 = 0.f, a2 = 0.f, a3 = 0.f;
#pragma unroll
    for (int k = 0; k < LH; k += 4) {
      float4 h4 = *reinterpret_cast<const float4*>(&hs[k]);
      a0 = fmaf(wr[k],   h4.x, a0);
      a1 = fmaf(wr[k+1], h4.y, a1);
      a2 = fmaf(wr[k+2], h4.z, a2);
      a3 = fmaf(wr[k+3], h4.w, a3);
    }
    sA[g] = ((a0 + a1) + (a2 + a3)) + bg;
    __syncthreads();
    if (g < LH) {
      float hr = sA[g],        xr = sX[g];
      float hz = sA[g+LH],     xz = sX[g+LH];
      float hn = sA[g+2*LH],   xn = sX[g+2*LH];
      float r = 1.f / (1.f + expf(-(xr + hr)));
      float z = 1.f / (1.f + expf(-(xz + hz)));
      float n = tanhf(xn + r * hn);
      float hold = hs[g];
      float hnew = (1.f - z) * n + z * hold;
      hs[g] = hnew;
      hbuf[((size_t)t * BATCH + b) * 256 + dir * LH + g] = hnew;
    }
    __syncthreads();
    t = tn;
  }
}

// ---------------- K3: emissions[b][t][9] = hbuf . Wlin^T + blin -------------
__global__ __launch_bounds__(256) void k_emis(
    const float* __restrict__ hbuf, const float* __restrict__ Wlin,
    const float* __restrict__ blin, float* __restrict__ e,
    float* __restrict__ lossp)
{
  if (blockIdx.x == 0 && threadIdx.x == 0) *lossp = 0.f;
  const int lane = threadIdx.x & 63, w = threadIdx.x >> 6;
  const int tokm = blockIdx.x * 4 + w;          // m = b*256 + t
  const int b = tokm >> 8, tt = tokm & 255;
  const float4 h4 = *reinterpret_cast<const float4*>(
      hbuf + ((size_t)tt * BATCH + b) * 256 + lane * 4);
  float acc[NLAB];
#pragma unroll
  for (int j = 0; j < NLAB; ++j) {
    const float4 w4 = *reinterpret_cast<const float4*>(Wlin + j * 256 + lane * 4);
    acc[j] = h4.x * w4.x + h4.y * w4.y + h4.z * w4.z + h4.w * w4.w;
  }
#pragma unroll
  for (int j = 0; j < NLAB; ++j)
#pragma unroll
    for (int off = 32; off > 0; off >>= 1)
      acc[j] += __shfl_xor(acc[j], off);
  if (lane == 0) {
#pragma unroll
    for (int j = 0; j < NLAB; ++j)
      e[(size_t)tokm * NLAB + j] = acc[j] + blin[j];
  }
}

// ---------------- K4: Viterbi (blocks 0..31) + CRF LLH (blocks 32..63) ------
__global__ __launch_bounds__(64) void k_crf(
    const float* __restrict__ e, const int* __restrict__ labels,
    const float* __restrict__ trans, const float* __restrict__ start,
    const float* __restrict__ endv, float* __restrict__ dec_out,
    float* __restrict__ lossp)
{
  __shared__ unsigned char bp8[(T_LEN-1) * 16];
  const int lane = threadIdx.x;
  const int bid  = blockIdx.x;
  const int b    = bid & 31;
  const float* eb = e + (size_t)b * T_LEN * NLAB;

  float tcol[NLAB];
#pragma unroll
  for (int i = 0; i < NLAB; ++i)
    tcol[i] = (lane < NLAB) ? trans[i * NLAB + lane] : 0.f;
  float alpha = (lane < NLAB) ? (start[lane] + eb[lane]) : -3e38f;

  if (bid < BATCH) {
    // ---- Viterbi ----
    for (int s = 0; s < T_LEN - 1; ++s) {
      float et = (lane < NLAB) ? eb[(s + 1) * NLAB + lane] : 0.f;
      float sv[NLAB];
#pragma unroll
      for (int i = 0; i < NLAB; ++i) sv[i] = __shfl(alpha, i);
      float best = sv[0] + tcol[0]; int bi = 0;
#pragma unroll
      for (int i = 1; i < NLAB; ++i) {
        float a = sv[i] + tcol[i];
        if (a > best) { best = a; bi = i; }   // strict >: first-max, matches jnp.argmax
      }
      alpha = best + et;
      if (lane < NLAB) bp8[s * 16 + lane] = (unsigned char)bi;
    }
    float fin = alpha + ((lane < NLAB) ? endv[lane] : 0.f);
    int last = 0; float bv = __shfl(fin, 0);
#pragma unroll
    for (int j = 1; j < NLAB; ++j) {
      float v = __shfl(fin, j);
      if (v > bv) { bv = v; last = j; }
    }
    if (lane == 0) {
      int y = last;
      dec_out[b * T_LEN + (T_LEN - 1)] = (float)y;
      uint4 row = *reinterpret_cast<const uint4*>(&bp8[(T_LEN - 2) * 16]);
      for (int s = T_LEN - 2; s >= 0; --s) {
        uint4 nrow = row;
        if (s > 0) nrow = *reinterpret_cast<const uint4*>(&bp8[(s - 1) * 16]);
        unsigned wsel = (y < 4) ? row.x : ((y < 8) ? row.y : row.z);
        y = (int)((wsel >> ((y & 3) * 8)) & 0xffu);
        dec_out[b * T_LEN + s] = (float)y;
        row = nrow;
      }
    }
  } else {
    // ---- CRF log-likelihood ----
    float ca = alpha;
    for (int s = 0; s < T_LEN - 1; ++s) {
      float et = (lane < NLAB) ? eb[(s + 1) * NLAB + lane] : 0.f;
      float c[NLAB];
#pragma unroll
      for (int i = 0; i < NLAB; ++i) c[i] = __shfl(ca, i) + tcol[i];
      float m = c[0];
#pragma unroll
      for (int i = 1; i < NLAB; ++i) m = fmaxf(m, c[i]);
      float p = 0.f;
#pragma unroll
      for (int i = 0; i < NLAB; ++i) p += expf(c[i] - m);
      ca = m + logf(p) + et;
    }
    float fv[NLAB]; float mx = -3e38f;
#pragma unroll
    for (int j = 0; j < NLAB; ++j) {
      fv[j] = __shfl(ca, j) + endv[j];
      mx = fmaxf(mx, fv[j]);
    }
    float ps = 0.f;
#pragma unroll
    for (int j = 0; j < NLAB; ++j) ps += expf(fv[j] - mx);
    float denom = mx + logf(ps);

    const int* lb = labels + b * T_LEN;
    float part = 0.f;
    for (int t4 = 0; t4 < 4; ++t4) {
      int t = lane * 4 + t4;
      int l = lb[t];
      part += eb[t * NLAB + l];
      if (t > 0) part += trans[lb[t - 1] * NLAB + l];
    }
#pragma unroll
    for (int off = 32; off > 0; off >>= 1) part += __shfl_xor(part, off);
    if (lane == 0) {
      float num = part + start[lb[0]] + endv[lb[T_LEN - 1]];
      float llh = num - denom;
      atomicAdd(lossp, -llh * (1.0f / BATCH));
    }
  }
}

extern "C" void kernel_launch(void* const* d_in, const int* in_sizes, int n_in,
                              void* d_out, int out_size, void* d_ws, size_t ws_size,
                              hipStream_t stream) {
  const int*   ids    = (const int*)d_in[0];
  const int*   labels = (const int*)d_in[2];
  const float* emb    = (const float*)d_in[3];
  const float* Wihf   = (const float*)d_in[4];
  const float* Whhf   = (const float*)d_in[5];
  const float* bihf   = (const float*)d_in[6];
  const float* bhhf   = (const float*)d_in[7];
  const float* Wihb   = (const float*)d_in[8];
  const float* Whhb   = (const float*)d_in[9];
  const float* bihb   = (const float*)d_in[10];
  const float* bhhb   = (const float*)d_in[11];
  const float* Wlin   = (const float*)d_in[12];
  const float* blin   = (const float*)d_in[13];
  const float* trans  = (const float*)d_in[14];
  const float* start  = (const float*)d_in[15];
  const float* endv   = (const float*)d_in[16];

  float* xp    = (float*)d_ws;                       // [T][B][768]
  float* hbuf  = xp + (size_t)M_TOT * HID;           // [T][B][256]
  float* e     = hbuf + (size_t)M_TOT * 256;         // [B][T][9]
  float* out   = (float*)d_out;                      // decoded as floats
  float* lossp = out + M_TOT;                        // loss scalar

  k_gemm_xp<<<dim3(6, 64), 256, 0, stream>>>(ids, emb, Wihf, Wihb, bihf, bihb, xp);
  k_gru<<<64, 384, 0, stream>>>(xp, Whhf, Whhb, bhhf, bhhb, hbuf);
  k_emis<<<M_TOT / 4, 256, 0, stream>>>(hbuf, Wlin, blin, e, lossp);
  k_crf<<<64, 64, 0, stream>>>(e, labels, trans, start, endv, out, lossp);
}

// Round 2
// 594.105 us; speedup vs baseline: 1.2564x; 1.2564x over previous
//
#include <hip/hip_runtime.h>
#include <math.h>

#define T_LEN 256
#define BATCH 32
#define HID   768
#define GH    384   // 3*LSTM_H
#define LH    128   // LSTM_H
#define NLAB  9
#define M_TOT (T_LEN*BATCH)  // 8192

// ---------------- K1: xp[t][b][0:768] = emb[ids] @ [Wih_f;Wih_b]^T + bias ----
// 128x128 tile, BK=8, 256 threads, 8x8 per thread. m = t*32+b.
__global__ __launch_bounds__(256) void k_gemm_xp(
    const int* __restrict__ ids, const float* __restrict__ emb,
    const float* __restrict__ Wf, const float* __restrict__ Wb,
    const float* __restrict__ bihf, const float* __restrict__ bihb,
    float* __restrict__ xp)
{
  __shared__ __align__(16) float As[8*128];
  __shared__ __align__(16) float Bs[8*128];
  const int tid = threadIdx.x;
  const int m0 = blockIdx.y * 128, n0 = blockIdx.x * 128;
  const int lrow = tid >> 1, c4 = (tid & 1) * 4;

  const int gm = m0 + lrow;
  const int tt = gm >> 5, bb = gm & 31;
  const int tok = ids[bb * T_LEN + tt];
  const float* aptr = emb + (size_t)tok * HID + c4;
  const int gn = n0 + lrow;
  const float* bptr = (gn < GH ? Wf + (size_t)gn * HID
                               : Wb + (size_t)(gn - GH) * HID) + c4;

  const int tx = tid & 15, ty = tid >> 4;
  float acc[8][8];
#pragma unroll
  for (int u = 0; u < 8; ++u)
#pragma unroll
    for (int v = 0; v < 8; ++v) acc[u][v] = 0.f;

  for (int k0 = 0; k0 < HID; k0 += 8) {
    float4 av = *reinterpret_cast<const float4*>(aptr + k0);
    float4 bv = *reinterpret_cast<const float4*>(bptr + k0);
    __syncthreads();
    As[(c4+0)*128 + lrow] = av.x;  As[(c4+1)*128 + lrow] = av.y;
    As[(c4+2)*128 + lrow] = av.z;  As[(c4+3)*128 + lrow] = av.w;
    Bs[(c4+0)*128 + lrow] = bv.x;  Bs[(c4+1)*128 + lrow] = bv.y;
    Bs[(c4+2)*128 + lrow] = bv.z;  Bs[(c4+3)*128 + lrow] = bv.w;
    __syncthreads();
#pragma unroll
    for (int kk = 0; kk < 8; ++kk) {
      float4 a0 = *reinterpret_cast<const float4*>(&As[kk*128 + ty*4]);
      float4 a1 = *reinterpret_cast<const float4*>(&As[kk*128 + 64 + ty*4]);
      float4 b0 = *reinterpret_cast<const float4*>(&Bs[kk*128 + tx*4]);
      float4 b1 = *reinterpret_cast<const float4*>(&Bs[kk*128 + 64 + tx*4]);
      float a[8] = {a0.x,a0.y,a0.z,a0.w,a1.x,a1.y,a1.z,a1.w};
      float b[8] = {b0.x,b0.y,b0.z,b0.w,b1.x,b1.y,b1.z,b1.w};
#pragma unroll
      for (int u = 0; u < 8; ++u)
#pragma unroll
        for (int v = 0; v < 8; ++v)
          acc[u][v] = fmaf(a[u], b[v], acc[u][v]);
    }
  }

  float bb8[8];
#pragma unroll
  for (int v = 0; v < 8; ++v) {
    int gc = n0 + tx*4 + (v & 3) + ((v >> 2) << 6);
    bb8[v] = (gc < GH) ? bihf[gc] : bihb[gc - GH];
  }
#pragma unroll
  for (int u = 0; u < 8; ++u) {
    int row = m0 + ty*4 + (u & 3) + ((u >> 2) << 6);
    float* orow = xp + (size_t)row * HID + n0;
    float4 o0, o1;
    o0.x = acc[u][0] + bb8[0]; o0.y = acc[u][1] + bb8[1];
    o0.z = acc[u][2] + bb8[2]; o0.w = acc[u][3] + bb8[3];
    o1.x = acc[u][4] + bb8[4]; o1.y = acc[u][5] + bb8[5];
    o1.z = acc[u][6] + bb8[6]; o1.w = acc[u][7] + bb8[7];
    *reinterpret_cast<float4*>(orow + tx*4)      = o0;
    *reinterpret_cast<float4*>(orow + 64 + tx*4) = o1;
  }
}

// ---------------- K2: bidirectional GRU recurrence (v2) ---------------------
// 64 blocks = (dir, batch); 256 threads = (unit g, K-half).
// Thread (g,half) holds Whh rows {g, g+128, g+256}, cols [half*64, half*64+64)
// in 192 VGPRs (reuse x3 on every LDS h-read). Pair reduction via shfl_xor(1).
// Double-buffered hs -> ONE barrier per step. Fast exp activations.
__global__ __launch_bounds__(256, 1) void k_gru(
    const float* __restrict__ xp,
    const float* __restrict__ Whhf, const float* __restrict__ Whhb,
    const float* __restrict__ bhhf, const float* __restrict__ bhhb,
    float* __restrict__ hbuf)
{
  __shared__ __align__(16) float hs[2][LH];
  const int tid  = threadIdx.x;
  const int g    = tid >> 1;      // hidden unit 0..127
  const int half = tid & 1;       // K-half
  const int bd   = blockIdx.x;
  const int dir  = bd >> 5, b = bd & 31;
  const float* Whh = dir ? Whhb : Whhf;
  const float* bhh = dir ? bhhb : bhhf;

  float w[3][64];
#pragma unroll
  for (int gate = 0; gate < 3; ++gate) {
    const float* wrow = Whh + (size_t)(gate * LH + g) * LH + half * 64;
#pragma unroll
    for (int k = 0; k < 64; k += 4) {
      float4 w4 = *reinterpret_cast<const float4*>(wrow + k);
      w[gate][k] = w4.x; w[gate][k+1] = w4.y; w[gate][k+2] = w4.z; w[gate][k+3] = w4.w;
    }
  }
  const float br = bhh[g], bz = bhh[g + LH], bn = bhh[g + 2*LH];

  if (tid < LH) hs[0][tid] = 0.f;

  const int t0   = dir ? (T_LEN - 1) : 0;
  const int dt   = dir ? -1 : 1;
  const int xoff = dir * GH;
  const float* xbase = xp + (size_t)b * HID + xoff + g;
  float* hob = hbuf + (size_t)b * 256 + dir * LH + g;

  float xr = 0.f, xz = 0.f, xn = 0.f;
  if (!half) {
    const float* p = xbase + (size_t)t0 * BATCH * HID;
    xr = p[0]; xz = p[LH]; xn = p[2*LH];
  }
  float hprev = 0.f;
  __syncthreads();

  int t = t0;
  for (int step = 0; step < T_LEN; ++step) {
    const int tn = (step < T_LEN - 1) ? (t + dt) : t;
    // prefetch next-step x (off critical path)
    float xrn = 0.f, xzn = 0.f, xnn = 0.f;
    if (!half) {
      const float* p = xbase + (size_t)tn * BATCH * HID;
      xrn = p[0]; xzn = p[LH]; xnn = p[2*LH];
    }

    const float* hc = &hs[step & 1][half * 64];
    float ar0=0.f, ar1=0.f, az0=0.f, az1=0.f, an0=0.f, an1=0.f;
#pragma unroll
    for (int k = 0; k < 64; k += 8) {
      float4 ha = *reinterpret_cast<const float4*>(hc + k);
      float4 hb = *reinterpret_cast<const float4*>(hc + k + 4);
      ar0 = fmaf(w[0][k+0], ha.x, ar0); ar0 = fmaf(w[0][k+1], ha.y, ar0);
      ar0 = fmaf(w[0][k+2], ha.z, ar0); ar0 = fmaf(w[0][k+3], ha.w, ar0);
      az0 = fmaf(w[1][k+0], ha.x, az0); az0 = fmaf(w[1][k+1], ha.y, az0);
      az0 = fmaf(w[1][k+2], ha.z, az0); az0 = fmaf(w[1][k+3], ha.w, az0);
      an0 = fmaf(w[2][k+0], ha.x, an0); an0 = fmaf(w[2][k+1], ha.y, an0);
      an0 = fmaf(w[2][k+2], ha.z, an0); an0 = fmaf(w[2][k+3], ha.w, an0);
      ar1 = fmaf(w[0][k+4], hb.x, ar1); ar1 = fmaf(w[0][k+5], hb.y, ar1);
      ar1 = fmaf(w[0][k+6], hb.z, ar1); ar1 = fmaf(w[0][k+7], hb.w, ar1);
      az1 = fmaf(w[1][k+4], hb.x, az1); az1 = fmaf(w[1][k+5], hb.y, az1);
      az1 = fmaf(w[1][k+6], hb.z, az1); az1 = fmaf(w[1][k+7], hb.w, az1);
      an1 = fmaf(w[2][k+4], hb.x, an1); an1 = fmaf(w[2][k+5], hb.y, an1);
      an1 = fmaf(w[2][k+6], hb.z, an1); an1 = fmaf(w[2][k+7], hb.w, an1);
    }
    float ar = ar0 + ar1, az = az0 + az1, an = an0 + an1;
    ar += __shfl_xor(ar, 1);
    az += __shfl_xor(az, 1);
    an += __shfl_xor(an, 1);

    if (!half) {
      float r  = 1.f / (1.f + __expf(-(xr + ar + br)));
      float z  = 1.f / (1.f + __expf(-(xz + az + bz)));
      float e2 = __expf(2.f * (xn + r * (an + bn)));
      float n  = (e2 - 1.f) / (e2 + 1.f);
      float hnew = (1.f - z) * n + z * hprev;
      hprev = hnew;
      hs[(step + 1) & 1][g] = hnew;
      hob[(size_t)t * BATCH * 256] = hnew;
    }
    __syncthreads();
    xr = xrn; xz = xzn; xn = xnn;
    t = tn;
  }
}

// ---------------- K3: emissions[b][t][9] = hbuf . Wlin^T + blin -------------
__global__ __launch_bounds__(256) void k_emis(
    const float* __restrict__ hbuf, const float* __restrict__ Wlin,
    const float* __restrict__ blin, float* __restrict__ e,
    float* __restrict__ lossp)
{
  if (blockIdx.x == 0 && threadIdx.x == 0) *lossp = 0.f;
  const int lane = threadIdx.x & 63, w = threadIdx.x >> 6;
  const int tokm = blockIdx.x * 4 + w;          // m = b*256 + t
  const int b = tokm >> 8, tt = tokm & 255;
  const float4 h4 = *reinterpret_cast<const float4*>(
      hbuf + ((size_t)tt * BATCH + b) * 256 + lane * 4);
  float acc[NLAB];
#pragma unroll
  for (int j = 0; j < NLAB; ++j) {
    const float4 w4 = *reinterpret_cast<const float4*>(Wlin + j * 256 + lane * 4);
    acc[j] = h4.x * w4.x + h4.y * w4.y + h4.z * w4.z + h4.w * w4.w;
  }
#pragma unroll
  for (int j = 0; j < NLAB; ++j)
#pragma unroll
    for (int off = 32; off > 0; off >>= 1)
      acc[j] += __shfl_xor(acc[j], off);
  if (lane == 0) {
#pragma unroll
    for (int j = 0; j < NLAB; ++j)
      e[(size_t)tokm * NLAB + j] = acc[j] + blin[j];
  }
}

// ---------------- K4: Viterbi (blocks 0..31) + CRF LLH (blocks 32..63) ------
__global__ __launch_bounds__(64) void k_crf(
    const float* __restrict__ e, const int* __restrict__ labels,
    const float* __restrict__ trans, const float* __restrict__ start,
    const float* __restrict__ endv, float* __restrict__ dec_out,
    float* __restrict__ lossp)
{
  __shared__ unsigned char bp8[(T_LEN-1) * 16];
  const int lane = threadIdx.x;
  const int bid  = blockIdx.x;
  const int b    = bid & 31;
  const float* eb = e + (size_t)b * T_LEN * NLAB;

  float tcol[NLAB];
#pragma unroll
  for (int i = 0; i < NLAB; ++i)
    tcol[i] = (lane < NLAB) ? trans[i * NLAB + lane] : 0.f;
  float alpha = (lane < NLAB) ? (start[lane] + eb[lane]) : -3e38f;

  if (bid < BATCH) {
    // ---- Viterbi ----
    for (int s = 0; s < T_LEN - 1; ++s) {
      float et = (lane < NLAB) ? eb[(s + 1) * NLAB + lane] : 0.f;
      float sv[NLAB];
#pragma unroll
      for (int i = 0; i < NLAB; ++i) sv[i] = __shfl(alpha, i);
      float best = sv[0] + tcol[0]; int bi = 0;
#pragma unroll
      for (int i = 1; i < NLAB; ++i) {
        float a = sv[i] + tcol[i];
        if (a > best) { best = a; bi = i; }   // strict >: first-max, matches jnp.argmax
      }
      alpha = best + et;
      if (lane < NLAB) bp8[s * 16 + lane] = (unsigned char)bi;
    }
    float fin = alpha + ((lane < NLAB) ? endv[lane] : 0.f);
    int last = 0; float bv = __shfl(fin, 0);
#pragma unroll
    for (int j = 1; j < NLAB; ++j) {
      float v = __shfl(fin, j);
      if (v > bv) { bv = v; last = j; }
    }
    if (lane == 0) {
      int y = last;
      dec_out[b * T_LEN + (T_LEN - 1)] = (float)y;
      uint4 row = *reinterpret_cast<const uint4*>(&bp8[(T_LEN - 2) * 16]);
      for (int s = T_LEN - 2; s >= 0; --s) {
        uint4 nrow = row;
        if (s > 0) nrow = *reinterpret_cast<const uint4*>(&bp8[(s - 1) * 16]);
        unsigned wsel = (y < 4) ? row.x : ((y < 8) ? row.y : row.z);
        y = (int)((wsel >> ((y & 3) * 8)) & 0xffu);
        dec_out[b * T_LEN + s] = (float)y;
        row = nrow;
      }
    }
  } else {
    // ---- CRF log-likelihood ----
    float ca = alpha;
    for (int s = 0; s < T_LEN - 1; ++s) {
      float et = (lane < NLAB) ? eb[(s + 1) * NLAB + lane] : 0.f;
      float c[NLAB];
#pragma unroll
      for (int i = 0; i < NLAB; ++i) c[i] = __shfl(ca, i) + tcol[i];
      float m = c[0];
#pragma unroll
      for (int i = 1; i < NLAB; ++i) m = fmaxf(m, c[i]);
      float p = 0.f;
#pragma unroll
      for (int i = 0; i < NLAB; ++i) p += expf(c[i] - m);
      ca = m + logf(p) + et;
    }
    float fv[NLAB]; float mx = -3e38f;
#pragma unroll
    for (int j = 0; j < NLAB; ++j) {
      fv[j] = __shfl(ca, j) + endv[j];
      mx = fmaxf(mx, fv[j]);
    }
    float ps = 0.f;
#pragma unroll
    for (int j = 0; j < NLAB; ++j) ps += expf(fv[j] - mx);
    float denom = mx + logf(ps);

    const int* lb = labels + b * T_LEN;
    float part = 0.f;
    for (int t4 = 0; t4 < 4; ++t4) {
      int t = lane * 4 + t4;
      int l = lb[t];
      part += eb[t * NLAB + l];
      if (t > 0) part += trans[lb[t - 1] * NLAB + l];
    }
#pragma unroll
    for (int off = 32; off > 0; off >>= 1) part += __shfl_xor(part, off);
    if (lane == 0) {
      float num = part + start[lb[0]] + endv[lb[T_LEN - 1]];
      float llh = num - denom;
      atomicAdd(lossp, -llh * (1.0f / BATCH));
    }
  }
}

extern "C" void kernel_launch(void* const* d_in, const int* in_sizes, int n_in,
                              void* d_out, int out_size, void* d_ws, size_t ws_size,
                              hipStream_t stream) {
  const int*   ids    = (const int*)d_in[0];
  const int*   labels = (const int*)d_in[2];
  const float* emb    = (const float*)d_in[3];
  const float* Wihf   = (const float*)d_in[4];
  const float* Whhf   = (const float*)d_in[5];
  const float* bihf   = (const float*)d_in[6];
  const float* bhhf   = (const float*)d_in[7];
  const float* Wihb   = (const float*)d_in[8];
  const float* Whhb   = (const float*)d_in[9];
  const float* bihb   = (const float*)d_in[10];
  const float* bhhb   = (const float*)d_in[11];
  const float* Wlin   = (const float*)d_in[12];
  const float* blin   = (const float*)d_in[13];
  const float* trans  = (const float*)d_in[14];
  const float* start  = (const float*)d_in[15];
  const float* endv   = (const float*)d_in[16];

  float* xp    = (float*)d_ws;                       // [T][B][768]
  float* hbuf  = xp + (size_t)M_TOT * HID;           // [T][B][256]
  float* e     = hbuf + (size_t)M_TOT * 256;         // [B][T][9]
  float* out   = (float*)d_out;                      // decoded as floats
  float* lossp = out + M_TOT;                        // loss scalar

  k_gemm_xp<<<dim3(6, 64), 256, 0, stream>>>(ids, emb, Wihf, Wihb, bihf, bihb, xp);
  k_gru<<<64, 256, 0, stream>>>(xp, Whhf, Whhb, bhhf, bhhb, hbuf);
  k_emis<<<M_TOT / 4, 256, 0, stream>>>(hbuf, Wlin, blin, e, lossp);
  k_crf<<<64, 64, 0, stream>>>(e, labels, trans, start, endv, out, lossp);
}

// Round 3
// 566.039 us; speedup vs baseline: 1.3187x; 1.0496x over previous
//
#include <hip/hip_runtime.h>
#include <math.h>

#define T_LEN 256
#define BATCH 32
#define HID   768
#define GH    384   // 3*LSTM_H
#define LH    128   // LSTM_H
#define NLAB  9
#define M_TOT (T_LEN*BATCH)  // 8192

typedef float v2f __attribute__((ext_vector_type(2)));

// ---------------- K1: xp[t][b][0:768] = emb[ids] @ [Wih_f;Wih_b]^T + bias ----
__global__ __launch_bounds__(256) void k_gemm_xp(
    const int* __restrict__ ids, const float* __restrict__ emb,
    const float* __restrict__ Wf, const float* __restrict__ Wb,
    const float* __restrict__ bihf, const float* __restrict__ bihb,
    float* __restrict__ xp)
{
  __shared__ __align__(16) float As[8*128];
  __shared__ __align__(16) float Bs[8*128];
  const int tid = threadIdx.x;
  const int m0 = blockIdx.y * 128, n0 = blockIdx.x * 128;
  const int lrow = tid >> 1, c4 = (tid & 1) * 4;

  const int gm = m0 + lrow;
  const int tt = gm >> 5, bb = gm & 31;
  const int tok = ids[bb * T_LEN + tt];
  const float* aptr = emb + (size_t)tok * HID + c4;
  const int gn = n0 + lrow;
  const float* bptr = (gn < GH ? Wf + (size_t)gn * HID
                               : Wb + (size_t)(gn - GH) * HID) + c4;

  const int tx = tid & 15, ty = tid >> 4;
  float acc[8][8];
#pragma unroll
  for (int u = 0; u < 8; ++u)
#pragma unroll
    for (int v = 0; v < 8; ++v) acc[u][v] = 0.f;

  for (int k0 = 0; k0 < HID; k0 += 8) {
    float4 av = *reinterpret_cast<const float4*>(aptr + k0);
    float4 bv = *reinterpret_cast<const float4*>(bptr + k0);
    __syncthreads();
    As[(c4+0)*128 + lrow] = av.x;  As[(c4+1)*128 + lrow] = av.y;
    As[(c4+2)*128 + lrow] = av.z;  As[(c4+3)*128 + lrow] = av.w;
    Bs[(c4+0)*128 + lrow] = bv.x;  Bs[(c4+1)*128 + lrow] = bv.y;
    Bs[(c4+2)*128 + lrow] = bv.z;  Bs[(c4+3)*128 + lrow] = bv.w;
    __syncthreads();
#pragma unroll
    for (int kk = 0; kk < 8; ++kk) {
      float4 a0 = *reinterpret_cast<const float4*>(&As[kk*128 + ty*4]);
      float4 a1 = *reinterpret_cast<const float4*>(&As[kk*128 + 64 + ty*4]);
      float4 b0 = *reinterpret_cast<const float4*>(&Bs[kk*128 + tx*4]);
      float4 b1 = *reinterpret_cast<const float4*>(&Bs[kk*128 + 64 + tx*4]);
      float a[8] = {a0.x,a0.y,a0.z,a0.w,a1.x,a1.y,a1.z,a1.w};
      float b[8] = {b0.x,b0.y,b0.z,b0.w,b1.x,b1.y,b1.z,b1.w};
#pragma unroll
      for (int u = 0; u < 8; ++u)
#pragma unroll
        for (int v = 0; v < 8; ++v)
          acc[u][v] = fmaf(a[u], b[v], acc[u][v]);
    }
  }

  float bb8[8];
#pragma unroll
  for (int v = 0; v < 8; ++v) {
    int gc = n0 + tx*4 + (v & 3) + ((v >> 2) << 6);
    bb8[v] = (gc < GH) ? bihf[gc] : bihb[gc - GH];
  }
#pragma unroll
  for (int u = 0; u < 8; ++u) {
    int row = m0 + ty*4 + (u & 3) + ((u >> 2) << 6);
    float* orow = xp + (size_t)row * HID + n0;
    float4 o0, o1;
    o0.x = acc[u][0] + bb8[0]; o0.y = acc[u][1] + bb8[1];
    o0.z = acc[u][2] + bb8[2]; o0.w = acc[u][3] + bb8[3];
    o1.x = acc[u][4] + bb8[4]; o1.y = acc[u][5] + bb8[5];
    o1.z = acc[u][6] + bb8[6]; o1.w = acc[u][7] + bb8[7];
    *reinterpret_cast<float4*>(orow + tx*4)      = o0;
    *reinterpret_cast<float4*>(orow + 64 + tx*4) = o1;
  }
}

// ---------------- K2: bidirectional GRU recurrence (v3) ---------------------
// 64 blocks = (dir, batch); 512 threads = (unit g = tid>>2, K-quarter q = tid&3).
// Per-thread weights w[3][32] = 96 VGPRs -> no spill (vs v2's 192 -> AGPR moves).
// LDS h padded: h[j] at hsp[buf][36*(j>>5) + (j&31)] so the 4 quarter addresses
// per ds_read_b128 land on disjoint bank groups (36 mod 32 = 4). Double-buffered,
// ONE barrier/step. float2 fma for v_pk_fma_f32. rcp instead of slow fp32 div.
__global__ __launch_bounds__(512, 2) void k_gru(
    const float* __restrict__ xp,
    const float* __restrict__ Whhf, const float* __restrict__ Whhb,
    const float* __restrict__ bhhf, const float* __restrict__ bhhb,
    float* __restrict__ hbuf)
{
  __shared__ __align__(16) float hsp[2][144];
  const int tid = threadIdx.x;
  const int g   = tid >> 2;     // hidden unit 0..127
  const int q   = tid & 3;      // K-quarter
  const int bd  = blockIdx.x;
  const int dir = bd >> 5, b = bd & 31;
  const float* Whh = dir ? Whhb : Whhf;
  const float* bhh = dir ? bhhb : bhhf;

  v2f w[3][16];
#pragma unroll
  for (int gate = 0; gate < 3; ++gate) {
    const float* wrow = Whh + (size_t)(gate * LH + g) * LH + q * 32;
#pragma unroll
    for (int j = 0; j < 8; ++j) {
      float4 w4 = *reinterpret_cast<const float4*>(wrow + j * 4);
      w[gate][2*j]   = v2f{w4.x, w4.y};
      w[gate][2*j+1] = v2f{w4.z, w4.w};
    }
  }
  const float br = bhh[g], bz = bhh[g + LH], bn = bhh[g + 2*LH];

  if (tid < LH) hsp[0][36*(tid >> 5) + (tid & 31)] = 0.f;

  const int t0   = dir ? (T_LEN - 1) : 0;
  const int dt   = dir ? -1 : 1;
  const float* xbase = xp + (size_t)b * HID + dir * GH + g;
  float* hob = hbuf + (size_t)b * 256 + dir * LH + g;

  float xr = 0.f, xz = 0.f, xn = 0.f;
  if (q == 0) {
    const float* p = xbase + (size_t)t0 * BATCH * HID;
    xr = p[0]; xz = p[LH]; xn = p[2*LH];
  }
  float hprev = 0.f;
  __syncthreads();

  int t = t0;
  for (int step = 0; step < T_LEN; ++step) {
    const int tn = (step < T_LEN - 1) ? (t + dt) : t;
    float xrn = 0.f, xzn = 0.f, xnn = 0.f;
    if (q == 0) {
      const float* p = xbase + (size_t)tn * BATCH * HID;
      xrn = p[0]; xzn = p[LH]; xnn = p[2*LH];
    }

    const float* hc = &hsp[step & 1][36 * q];
    v2f ar0 = v2f{0.f,0.f}, ar1 = ar0, az0 = ar0, az1 = ar0, an0 = ar0, an1 = ar0;
#pragma unroll
    for (int j = 0; j < 4; ++j) {
      float4 ha = *reinterpret_cast<const float4*>(hc + 8*j);
      float4 hb = *reinterpret_cast<const float4*>(hc + 8*j + 4);
      v2f h0 = v2f{ha.x, ha.y}, h1 = v2f{ha.z, ha.w};
      v2f h2 = v2f{hb.x, hb.y}, h3 = v2f{hb.z, hb.w};
      ar0 = __builtin_elementwise_fma(w[0][4*j+0], h0, ar0);
      ar1 = __builtin_elementwise_fma(w[0][4*j+1], h1, ar1);
      ar0 = __builtin_elementwise_fma(w[0][4*j+2], h2, ar0);
      ar1 = __builtin_elementwise_fma(w[0][4*j+3], h3, ar1);
      az0 = __builtin_elementwise_fma(w[1][4*j+0], h0, az0);
      az1 = __builtin_elementwise_fma(w[1][4*j+1], h1, az1);
      az0 = __builtin_elementwise_fma(w[1][4*j+2], h2, az0);
      az1 = __builtin_elementwise_fma(w[1][4*j+3], h3, az1);
      an0 = __builtin_elementwise_fma(w[2][4*j+0], h0, an0);
      an1 = __builtin_elementwise_fma(w[2][4*j+1], h1, an1);
      an0 = __builtin_elementwise_fma(w[2][4*j+2], h2, an0);
      an1 = __builtin_elementwise_fma(w[2][4*j+3], h3, an1);
    }
    float ar = (ar0.x + ar0.y) + (ar1.x + ar1.y);
    float az = (az0.x + az0.y) + (az1.x + az1.y);
    float an = (an0.x + an0.y) + (an1.x + an1.y);
    ar += __shfl_xor(ar, 1);  ar += __shfl_xor(ar, 2);
    az += __shfl_xor(az, 1);  az += __shfl_xor(az, 2);
    an += __shfl_xor(an, 1);  an += __shfl_xor(an, 2);

    if (q == 0) {
      float r  = __builtin_amdgcn_rcpf(1.f + __expf(-(xr + ar + br)));
      float z  = __builtin_amdgcn_rcpf(1.f + __expf(-(xz + az + bz)));
      float e2 = __expf(2.f * (xn + r * (an + bn)));
      float n  = (e2 - 1.f) * __builtin_amdgcn_rcpf(e2 + 1.f);
      float hnew = (1.f - z) * n + z * hprev;
      hprev = hnew;
      hsp[(step + 1) & 1][36*(g >> 5) + (g & 31)] = hnew;
      hob[(size_t)t * BATCH * 256] = hnew;
    }
    __syncthreads();
    xr = xrn; xz = xzn; xn = xnn;
    t = tn;
  }
}

// ---------------- K3: emissions[b][t][9] = hbuf . Wlin^T + blin -------------
__global__ __launch_bounds__(256) void k_emis(
    const float* __restrict__ hbuf, const float* __restrict__ Wlin,
    const float* __restrict__ blin, float* __restrict__ e,
    float* __restrict__ lossp)
{
  if (blockIdx.x == 0 && threadIdx.x == 0) *lossp = 0.f;
  const int lane = threadIdx.x & 63, w = threadIdx.x >> 6;
  const int tokm = blockIdx.x * 4 + w;          // m = b*256 + t
  const int b = tokm >> 8, tt = tokm & 255;
  const float4 h4 = *reinterpret_cast<const float4*>(
      hbuf + ((size_t)tt * BATCH + b) * 256 + lane * 4);
  float acc[NLAB];
#pragma unroll
  for (int j = 0; j < NLAB; ++j) {
    const float4 w4 = *reinterpret_cast<const float4*>(Wlin + j * 256 + lane * 4);
    acc[j] = h4.x * w4.x + h4.y * w4.y + h4.z * w4.z + h4.w * w4.w;
  }
#pragma unroll
  for (int j = 0; j < NLAB; ++j)
#pragma unroll
    for (int off = 32; off > 0; off >>= 1)
      acc[j] += __shfl_xor(acc[j], off);
  if (lane == 0) {
#pragma unroll
    for (int j = 0; j < NLAB; ++j)
      e[(size_t)tokm * NLAB + j] = acc[j] + blin[j];
  }
}

// ---------------- K4: Viterbi (blocks 0..31) + CRF LLH (blocks 32..63) ------
__global__ __launch_bounds__(64) void k_crf(
    const float* __restrict__ e, const int* __restrict__ labels,
    const float* __restrict__ trans, const float* __restrict__ start,
    const float* __restrict__ endv, float* __restrict__ dec_out,
    float* __restrict__ lossp)
{
  __shared__ unsigned char bp8[(T_LEN-1) * 16];
  const int lane = threadIdx.x;
  const int bid  = blockIdx.x;
  const int b    = bid & 31;
  const float* eb = e + (size_t)b * T_LEN * NLAB;

  float tcol[NLAB];
#pragma unroll
  for (int i = 0; i < NLAB; ++i)
    tcol[i] = (lane < NLAB) ? trans[i * NLAB + lane] : 0.f;
  float alpha = (lane < NLAB) ? (start[lane] + eb[lane]) : -3e38f;

  if (bid < BATCH) {
    // ---- Viterbi ----
    for (int s = 0; s < T_LEN - 1; ++s) {
      float et = (lane < NLAB) ? eb[(s + 1) * NLAB + lane] : 0.f;
      float sv[NLAB];
#pragma unroll
      for (int i = 0; i < NLAB; ++i) sv[i] = __shfl(alpha, i);
      float best = sv[0] + tcol[0]; int bi = 0;
#pragma unroll
      for (int i = 1; i < NLAB; ++i) {
        float a = sv[i] + tcol[i];
        if (a > best) { best = a; bi = i; }   // strict >: first-max, matches jnp.argmax
      }
      alpha = best + et;
      if (lane < NLAB) bp8[s * 16 + lane] = (unsigned char)bi;
    }
    float fin = alpha + ((lane < NLAB) ? endv[lane] : 0.f);
    int last = 0; float bv = __shfl(fin, 0);
#pragma unroll
    for (int j = 1; j < NLAB; ++j) {
      float v = __shfl(fin, j);
      if (v > bv) { bv = v; last = j; }
    }
    if (lane == 0) {
      int y = last;
      dec_out[b * T_LEN + (T_LEN - 1)] = (float)y;
      uint4 row = *reinterpret_cast<const uint4*>(&bp8[(T_LEN - 2) * 16]);
      for (int s = T_LEN - 2; s >= 0; --s) {
        uint4 nrow = row;
        if (s > 0) nrow = *reinterpret_cast<const uint4*>(&bp8[(s - 1) * 16]);
        unsigned wsel = (y < 4) ? row.x : ((y < 8) ? row.y : row.z);
        y = (int)((wsel >> ((y & 3) * 8)) & 0xffu);
        dec_out[b * T_LEN + s] = (float)y;
        row = nrow;
      }
    }
  } else {
    // ---- CRF log-likelihood ----
    float ca = alpha;
    for (int s = 0; s < T_LEN - 1; ++s) {
      float et = (lane < NLAB) ? eb[(s + 1) * NLAB + lane] : 0.f;
      float c[NLAB];
#pragma unroll
      for (int i = 0; i < NLAB; ++i) c[i] = __shfl(ca, i) + tcol[i];
      float m = c[0];
#pragma unroll
      for (int i = 1; i < NLAB; ++i) m = fmaxf(m, c[i]);
      float p = 0.f;
#pragma unroll
      for (int i = 0; i < NLAB; ++i) p += expf(c[i] - m);
      ca = m + logf(p) + et;
    }
    float fv[NLAB]; float mx = -3e38f;
#pragma unroll
    for (int j = 0; j < NLAB; ++j) {
      fv[j] = __shfl(ca, j) + endv[j];
      mx = fmaxf(mx, fv[j]);
    }
    float ps = 0.f;
#pragma unroll
    for (int j = 0; j < NLAB; ++j) ps += expf(fv[j] - mx);
    float denom = mx + logf(ps);

    const int* lb = labels + b * T_LEN;
    float part = 0.f;
    for (int t4 = 0; t4 < 4; ++t4) {
      int t = lane * 4 + t4;
      int l = lb[t];
      part += eb[t * NLAB + l];
      if (t > 0) part += trans[lb[t - 1] * NLAB + l];
    }
#pragma unroll
    for (int off = 32; off > 0; off >>= 1) part += __shfl_xor(part, off);
    if (lane == 0) {
      float num = part + start[lb[0]] + endv[lb[T_LEN - 1]];
      float llh = num - denom;
      atomicAdd(lossp, -llh * (1.0f / BATCH));
    }
  }
}

extern "C" void kernel_launch(void* const* d_in, const int* in_sizes, int n_in,
                              void* d_out, int out_size, void* d_ws, size_t ws_size,
                              hipStream_t stream) {
  const int*   ids    = (const int*)d_in[0];
  const int*   labels = (const int*)d_in[2];
  const float* emb    = (const float*)d_in[3];
  const float* Wihf   = (const float*)d_in[4];
  const float* Whhf   = (const float*)d_in[5];
  const float* bihf   = (const float*)d_in[6];
  const float* bhhf   = (const float*)d_in[7];
  const float* Wihb   = (const float*)d_in[8];
  const float* Whhb   = (const float*)d_in[9];
  const float* bihb   = (const float*)d_in[10];
  const float* bhhb   = (const float*)d_in[11];
  const float* Wlin   = (const float*)d_in[12];
  const float* blin   = (const float*)d_in[13];
  const float* trans  = (const float*)d_in[14];
  const float* start  = (const float*)d_in[15];
  const float* endv   = (const float*)d_in[16];

  float* xp    = (float*)d_ws;                       // [T][B][768]
  float* hbuf  = xp + (size_t)M_TOT * HID;           // [T][B][256]
  float* e     = hbuf + (size_t)M_TOT * 256;         // [B][T][9]
  float* out   = (float*)d_out;                      // decoded as floats
  float* lossp = out + M_TOT;                        // loss scalar

  k_gemm_xp<<<dim3(6, 64), 256, 0, stream>>>(ids, emb, Wihf, Wihb, bihf, bihb, xp);
  k_gru<<<64, 512, 0, stream>>>(xp, Whhf, Whhb, bhhf, bhhb, hbuf);
  k_emis<<<M_TOT / 4, 256, 0, stream>>>(hbuf, Wlin, blin, e, lossp);
  k_crf<<<64, 64, 0, stream>>>(e, labels, trans, start, endv, out, lossp);
}